// Round 7
// baseline (136.135 us; speedup 1.0000x reference)
//
#include <hip/hip_runtime.h>

// TT-linear: y = x[16384,784] @ W[784,512] + bias; out = softmax(relu(y), axis=1)
// conv_x  : x fp32 -> xt bf16, K padded to 832, swizzled into per-(mb,kt) 4KB
//           chunks in exact LDS fragment order (for global_load_lds DMA).
// prep_all: 225 blocks build W (bf16, MFMA B-fragment layout, 26 k-steps).
// tt_gemm : 512 blocks x 512 thr; block = 32 rows x 512 cols; wave = 32x64
//           (acc 2x4). A staged via global_load_lds (double-buffered 2x4KB),
//           B per-tile register loads from L2. 13 iters, 1 barrier each.
//
// ws: [0, 27262976)          xt bf16: [mb(512)][kt(13)][c(256)][j(8)]
//       c = ks*128 + mt*64 + quad*16 + lid
//       row = mb*32 + mt*16 + lid ; k = kt*64 + ks*32 + quad*8 + j
//     [27262976, 28114944)   wp bf16: [((tn*26 + tks)*64 + quad*16+lid)*8 + j]
//       = W[k=tks*32+quad*8+j][n=tn*16+lid]

typedef __attribute__((ext_vector_type(8))) short short8;
typedef __attribute__((ext_vector_type(4))) float floatx4;
typedef __attribute__((address_space(1))) const unsigned int gu32;
typedef __attribute__((address_space(3))) unsigned int lu32;

#define XT_OFF 0
#define WP_OFF 27262976

__device__ __forceinline__ unsigned int pack2_bf16(float a, float b) {
    unsigned int ua = __float_as_uint(a);
    unsigned int ub = __float_as_uint(b);
    return ((ub + 0x8000u) & 0xFFFF0000u) | ((ua + 0x8000u) >> 16);
}

__device__ __forceinline__ short f32_to_bf16_rne(float v) {
    unsigned int u = __float_as_uint(v);
    return (short)(((u + 0x7FFFu + ((u >> 16) & 1)) >> 16) & 0xFFFF);
}

// ---------- convert: x -> xt (bf16, swizzled, K=832). 6656 x 256, writes coalesced ----------
__global__ void conv_x(const float* __restrict__ x, short* __restrict__ xt) {
    const int g = blockIdx.x * 256 + threadIdx.x;     // chunk16 id, < 512*13*256
    const int c    = g & 255;
    const int mbkt = g >> 8;
    const int kt = mbkt % 13;
    const int mb = mbkt / 13;
    const int ks = c >> 7, mt = (c >> 6) & 1, quad = (c >> 4) & 3, lid = c & 15;
    const int row = mb * 32 + mt * 16 + lid;
    const int k0  = kt * 64 + ks * 32 + quad * 8;
    floatx4 v0 = {0.f, 0.f, 0.f, 0.f}, v1 = {0.f, 0.f, 0.f, 0.f};
    if (k0 < 784) {
        const floatx4* p = (const floatx4*)(x + (size_t)row * 784 + k0);
        v0 = p[0]; v1 = p[1];
    }
    union { short8 s; unsigned int u[4]; } af;
    af.u[0] = pack2_bf16(v0.x, v0.y);
    af.u[1] = pack2_bf16(v0.z, v0.w);
    af.u[2] = pack2_bf16(v1.x, v1.y);
    af.u[3] = pack2_bf16(v1.z, v1.w);
    *(short8*)(xt + (size_t)g * 8) = af.s;
}

// ---------- prep: t12 -> t123 slice -> wp slice, 225 blocks x 256 ----------
__global__ void prep_all(const float* __restrict__ c1, const float* __restrict__ c2,
                         const float* __restrict__ c3, const float* __restrict__ c4,
                         short* __restrict__ wp) {
    const int tid = threadIdx.x;
    const int blk = blockIdx.x;
    if (blk == 224) {                      // zero wp for k in [784,832)
        for (int e = tid; e < 24576; e += 256) {
            int tn = e / 768;
            int r  = e % 768;
            int qq = r >> 7;
            int lid = (r >> 3) & 15;
            int j  = r & 7;
            int tks  = (qq < 2) ? 24 : 25;
            int quad = (qq < 2) ? (2 + qq) : (qq - 2);
            wp[(((tn * 26 + tks) * 64 + quad * 16 + lid) << 3) + j] = 0;
        }
        return;
    }
    __shared__ float t12s[320];            // [pq(16)][s(20)]
    __shared__ float t123s[7 * 256];       // [k3(7)][pql(16)][t(16)], pql=qloc*8+e3
    __shared__ float c4s[256];             // [t(16)][l(4)][f4(4)]

    const int ij    = blk >> 3;
    const int strip = blk & 7;
    const int i  = ij >> 2, j2 = ij & 3;
    const int p  = strip >> 1;
    const int qh = strip & 1;

    if (tid < 256) c4s[tid] = c4[tid];
    for (int e = tid; e < 320; e += 256) {
        int s = e % 20, pq = e / 20;
        int pp = pq >> 2, q = pq & 3;
        float acc = 0.f;
        #pragma unroll
        for (int r = 0; r < 20; ++r)
            acc += c1[i * 80 + pp * 20 + r] * c2[r * 320 + j2 * 80 + q * 20 + s];
        t12s[e] = acc;
    }
    __syncthreads();

    for (int e = tid; e < 1792; e += 256) {
        int k3 = e >> 8, li = e & 255;
        int t = li & 15, pql = li >> 4;
        int qloc = pql >> 3, e3 = pql & 7;
        int q = 2 * qh + qloc;
        float acc = 0.f;
        const float* tp = t12s + (p * 4 + q) * 20;
        const float* cp = c3 + k3 * 128 + e3 * 16 + t;
        #pragma unroll
        for (int s = 0; s < 20; ++s) acc += tp[s] * cp[s * 896];
        t123s[e] = acc;
    }
    __syncthreads();

    for (int e = tid; e < 1792; e += 256) {
        int kl = e >> 6, nl = e & 63;
        int k = ij * 28 + kl;
        int n = strip * 64 + nl;
        int k3 = kl >> 2, l = kl & 3;
        int f4 = n & 3, e3 = (n >> 2) & 7;
        int pql = ((n >> 5) & 1) * 8 + e3;
        const float* tp = t123s + k3 * 256 + pql * 16;
        const float* cq = c4s + l * 4 + f4;
        float a = 0.f;
        #pragma unroll
        for (int t = 0; t < 16; ++t) a += tp[t] * cq[t * 16];
        int tks = k >> 5, quad = (k >> 3) & 3, j = k & 7;
        int tn = n >> 4, lid = n & 15;
        wp[(((tn * 26 + tks) * 64 + quad * 16 + lid) << 3) + j] = f32_to_bf16_rne(a);
    }
}

// ---------- main GEMM + bias + relu + softmax ----------
// grid 512 (32 rows each), block 512 = 8 waves; wave w owns cols [w*64, w*64+64),
// acc 2x4. A: global_load_lds DMA from xt, double-buffered (2x4KB), waves 0..3
// each issue one dwordx4 DMA per chunk. B: per-tile 16B register loads from L2.
__global__ __launch_bounds__(512, 4) void tt_gemm(const short* __restrict__ xt,
                                                  const short* __restrict__ wp,
                                                  const float* __restrict__ bias,
                                                  float* __restrict__ out) {
    __shared__ __align__(16) short s_a[2][2048];   // 2 x 4 KB
    __shared__ float part[8][32];

    const int tid  = threadIdx.x;
    const int w    = tid >> 6;
    const int lane = tid & 63;
    const int quad = lane >> 4;
    const int lid  = lane & 15;
    const int mb   = blockIdx.x;
    const int m_base = mb * 32;

    const short* wpw = wp + ((size_t)(w * 4) * 26 * 64 + lane) * 8;   // tn = w*4 + nt

    // wave w (0..3) stages bytes [w*1024, w*1024+1024) of chunk (mb,kt) via DMA
    auto stage = [&](int kt, int buf) {
        if (w < 4) {
            const short* g = xt + (size_t)(mb * 13 + kt) * 2048 + w * 512 + lane * 8;
            __builtin_amdgcn_global_load_lds((gu32*)g, (lu32*)&s_a[buf][w * 512], 16, 0, 0);
        }
    };

    stage(0, 0);
    __syncthreads();

    floatx4 acc[2][4];
    #pragma unroll
    for (int mt = 0; mt < 2; ++mt)
        #pragma unroll
        for (int nt = 0; nt < 4; ++nt)
            acc[mt][nt] = floatx4{0.f, 0.f, 0.f, 0.f};

    #pragma unroll 1
    for (int kt = 0; kt < 13; ++kt) {
        if (kt + 1 < 13) stage(kt + 1, (kt + 1) & 1);   // DMA overlaps this chunk's compute

        const short* sab = &s_a[kt & 1][lane * 8];
        #pragma unroll
        for (int ks = 0; ks < 2; ++ks) {
            short8 a0 = *(const short8*)(sab + (ks * 128) * 8);
            short8 a1 = *(const short8*)(sab + (ks * 128 + 64) * 8);
            const int tks = kt * 2 + ks;
            #pragma unroll
            for (int nt = 0; nt < 4; ++nt) {
                short8 bf = *(const short8*)(wpw + (size_t)(nt * 26 + tks) * 64 * 8);
                acc[0][nt] = __builtin_amdgcn_mfma_f32_16x16x32_bf16(a0, bf, acc[0][nt], 0, 0, 0);
                acc[1][nt] = __builtin_amdgcn_mfma_f32_16x16x32_bf16(a1, bf, acc[1][nt], 0, 0, 0);
            }
        }
        __syncthreads();   // drains DMA for kt+1; guards buf reuse at kt+2
    }

    // ---- epilogue: bias + relu + exp, row sums across 8 waves, scale, store ----
    float bias_v[4];
    #pragma unroll
    for (int nt = 0; nt < 4; ++nt)
        bias_v[nt] = bias[w * 64 + nt * 16 + lid];

    #pragma unroll
    for (int mt = 0; mt < 2; ++mt) {
        #pragma unroll
        for (int reg = 0; reg < 4; ++reg) {
            float s = 0.f;
            #pragma unroll
            for (int nt = 0; nt < 4; ++nt) {
                float v = acc[mt][nt][reg] + bias_v[nt];
                v = fmaxf(v, 0.f);
                float e = __expf(v);
                acc[mt][nt][reg] = e;
                s += e;
            }
            s += __shfl_xor(s, 1, 64);
            s += __shfl_xor(s, 2, 64);
            s += __shfl_xor(s, 4, 64);
            s += __shfl_xor(s, 8, 64);
            if (lid == 0) part[w][mt * 16 + quad * 4 + reg] = s;
        }
    }
    __syncthreads();

    #pragma unroll
    for (int mt = 0; mt < 2; ++mt) {
        #pragma unroll
        for (int reg = 0; reg < 4; ++reg) {
            const int row = mt * 16 + quad * 4 + reg;
            float tot = 0.f;
            #pragma unroll
            for (int ww = 0; ww < 8; ++ww) tot += part[ww][row];
            const float inv = 1.0f / tot;
            #pragma unroll
            for (int nt = 0; nt < 4; ++nt)
                out[(size_t)(m_base + row) * 512 + w * 64 + nt * 16 + lid] = acc[mt][nt][reg] * inv;
        }
    }
}

extern "C" void kernel_launch(void* const* d_in, const int* in_sizes, int n_in,
                              void* d_out, int out_size, void* d_ws, size_t ws_size,
                              hipStream_t stream) {
    const float* x    = (const float*)d_in[0];
    const float* c1   = (const float*)d_in[1];
    const float* c2   = (const float*)d_in[2];
    const float* c3   = (const float*)d_in[3];
    const float* c4   = (const float*)d_in[4];
    const float* bias = (const float*)d_in[5];
    float* out = (float*)d_out;

    char* ws = (char*)d_ws;
    short* xt  = (short*)(ws + XT_OFF);
    short* wpb = (short*)(ws + WP_OFF);

    conv_x  <<<6656, 256, 0, stream>>>(x, xt);
    prep_all<<<225,  256, 0, stream>>>(c1, c2, c3, c4, wpb);
    tt_gemm <<<512,  512, 0, stream>>>(xt, wpb, bias, out);
}

// Round 9
// 131.476 us; speedup vs baseline: 1.0354x; 1.0354x over previous
//
#include <hip/hip_runtime.h>

// TT-linear: y = x[16384,784] @ W[784,512] + bias; out = softmax(relu(y), axis=1)
// prep_all: 225 blocks build W (bf16, MFMA B-fragment layout, 26 k-steps of 32).
// tt_gemm : grid 256, block 512 = 8 waves. Block = 64 rows x 512 cols; wave =
//           64x64 (acc 4x4). K-loop: 13 chunks of BK=64, LDS double-buffer
//           2x8KB, per-thread 8-float register prefetch of chunk kt+1 during
//           chunk kt's 32 MFMAs/wave. B per-tile 16B loads from L2 (213 MB
//           total, wp hot in every XCD L2). Fused bias+relu+softmax epilogue.
//
// LDS chunk layout (512 entries of 8 bf16): entry = ks*256 + mt*64 + quad*16 + lid
//   holds A[row = mt*16+lid][k = kt*64 + ks*32 + quad*8 + j], j=0..7
//
// ws: [0, 851968) wp bf16: [((tn*26 + tks)*64 + quad*16 + lid)*8 + j]
//     = W[k = tks*32 + quad*8 + j][n = tn*16 + lid]

typedef __attribute__((ext_vector_type(8))) short short8;
typedef __attribute__((ext_vector_type(4))) float floatx4;

__device__ __forceinline__ unsigned int pack2_bf16(float a, float b) {
    unsigned int ua = __float_as_uint(a);
    unsigned int ub = __float_as_uint(b);
    return ((ub + 0x8000u) & 0xFFFF0000u) | ((ua + 0x8000u) >> 16);
}

__device__ __forceinline__ short f32_to_bf16_rne(float v) {
    unsigned int u = __float_as_uint(v);
    return (short)(((u + 0x7FFFu + ((u >> 16) & 1)) >> 16) & 0xFFFF);
}

// ---------- prep: t12 -> t123 slice -> wp slice, 225 blocks x 256 ----------
__global__ void prep_all(const float* __restrict__ c1, const float* __restrict__ c2,
                         const float* __restrict__ c3, const float* __restrict__ c4,
                         short* __restrict__ wp) {
    const int tid = threadIdx.x;
    const int blk = blockIdx.x;
    if (blk == 224) {                      // zero wp for k in [784,832)
        for (int e = tid; e < 24576; e += 256) {
            int tn = e / 768;
            int r  = e % 768;
            int qq = r >> 7;
            int lid = (r >> 3) & 15;
            int j  = r & 7;
            int tks  = (qq < 2) ? 24 : 25;
            int quad = (qq < 2) ? (2 + qq) : (qq - 2);
            wp[(((tn * 26 + tks) * 64 + quad * 16 + lid) << 3) + j] = 0;
        }
        return;
    }
    __shared__ float t12s[320];            // [pq(16)][s(20)]
    __shared__ float t123s[7 * 256];       // [k3(7)][pql(16)][t(16)], pql=qloc*8+e3
    __shared__ float c4s[256];             // [t(16)][l(4)][f4(4)]

    const int ij    = blk >> 3;
    const int strip = blk & 7;
    const int i  = ij >> 2, j2 = ij & 3;
    const int p  = strip >> 1;
    const int qh = strip & 1;

    if (tid < 256) c4s[tid] = c4[tid];
    for (int e = tid; e < 320; e += 256) {
        int s = e % 20, pq = e / 20;
        int pp = pq >> 2, q = pq & 3;
        float acc = 0.f;
        #pragma unroll
        for (int r = 0; r < 20; ++r)
            acc += c1[i * 80 + pp * 20 + r] * c2[r * 320 + j2 * 80 + q * 20 + s];
        t12s[e] = acc;
    }
    __syncthreads();

    for (int e = tid; e < 1792; e += 256) {
        int k3 = e >> 8, li = e & 255;
        int t = li & 15, pql = li >> 4;
        int qloc = pql >> 3, e3 = pql & 7;
        int q = 2 * qh + qloc;
        float acc = 0.f;
        const float* tp = t12s + (p * 4 + q) * 20;
        const float* cp = c3 + k3 * 128 + e3 * 16 + t;
        #pragma unroll
        for (int s = 0; s < 20; ++s) acc += tp[s] * cp[s * 896];
        t123s[e] = acc;
    }
    __syncthreads();

    for (int e = tid; e < 1792; e += 256) {
        int kl = e >> 6, nl = e & 63;
        int k = ij * 28 + kl;
        int n = strip * 64 + nl;
        int k3 = kl >> 2, l = kl & 3;
        int f4 = n & 3, e3 = (n >> 2) & 7;
        int pql = ((n >> 5) & 1) * 8 + e3;
        const float* tp = t123s + k3 * 256 + pql * 16;
        const float* cq = c4s + l * 4 + f4;
        float a = 0.f;
        #pragma unroll
        for (int t = 0; t < 16; ++t) a += tp[t] * cq[t * 16];
        int tks = k >> 5, quad = (k >> 3) & 3, j = k & 7;
        int tn = n >> 4, lid = n & 15;
        wp[(((tn * 26 + tks) * 64 + quad * 16 + lid) << 3) + j] = f32_to_bf16_rne(a);
    }
}

// ---------- main GEMM + bias + relu + softmax ----------
__global__ __launch_bounds__(512, 2) void tt_gemm(const float* __restrict__ x,
                                                  const short* __restrict__ wp,
                                                  const float* __restrict__ bias,
                                                  float* __restrict__ out) {
    __shared__ __align__(16) short s_a[2][512 * 8];   // 2 x 8 KB
    __shared__ float part[8][64];

    const int tid  = threadIdx.x;
    const int w    = tid >> 6;
    const int lane = tid & 63;
    const int quad = lane >> 4;
    const int lid  = lane & 15;
    const int m_base = blockIdx.x * 64;

    // staging geometry: thread -> (row, 8 consecutive floats of the chunk)
    const int srow = tid >> 3;                       // 0..63
    const int sk8  = tid & 7;                        // 8-float group within BK=64
    const int sc   = (sk8 >> 2) * 256 + (srow >> 4) * 64 + (sk8 & 3) * 16 + (srow & 15);
    const float* xrow = x + (size_t)(m_base + srow) * 784 + sk8 * 8;
    short* sdst0 = &s_a[0][sc * 8];
    short* sdst1 = &s_a[1][sc * 8];

    const short* wpw = wp + ((size_t)(w * 4) * 26 * 64 + lane) * 8;   // tn = w*4 + nt

    // ---- stage chunk 0 (k in [0,64), no guard) ----
    {
        const floatx4* p = (const floatx4*)xrow;
        floatx4 v0 = p[0], v1 = p[1];
        union { short8 s; unsigned int u[4]; } af;
        af.u[0] = pack2_bf16(v0.x, v0.y);
        af.u[1] = pack2_bf16(v0.z, v0.w);
        af.u[2] = pack2_bf16(v1.x, v1.y);
        af.u[3] = pack2_bf16(v1.z, v1.w);
        *(short8*)sdst0 = af.s;
    }
    __syncthreads();

    floatx4 acc[4][4];
    #pragma unroll
    for (int mt = 0; mt < 4; ++mt)
        #pragma unroll
        for (int nt = 0; nt < 4; ++nt)
            acc[mt][nt] = floatx4{0.f, 0.f, 0.f, 0.f};

    #pragma unroll 1
    for (int kt = 0; kt < 13; ++kt) {
        // prefetch chunk kt+1 into 8 held VGPRs (issued before the MFMA block)
        floatx4 h0 = {0.f, 0.f, 0.f, 0.f}, h1 = {0.f, 0.f, 0.f, 0.f};
        if (kt < 12) {
            const int kg = (kt + 1) * 64 + sk8 * 8;
            if (kg < 784) {
                const floatx4* p = (const floatx4*)(xrow + (kt + 1) * 64);
                h0 = p[0]; h1 = p[1];
            }
        }

        const short* sab = &s_a[kt & 1][lane * 8];
        #pragma unroll
        for (int ks = 0; ks < 2; ++ks) {
            short8 af[4], bf[4];
            #pragma unroll
            for (int mt = 0; mt < 4; ++mt)
                af[mt] = *(const short8*)(sab + (ks * 256 + mt * 64) * 8);
            #pragma unroll
            for (int nt = 0; nt < 4; ++nt)
                bf[nt] = *(const short8*)(wpw + (size_t)(nt * 26 + kt * 2 + ks) * 64 * 8);
            #pragma unroll
            for (int nt = 0; nt < 4; ++nt)
                #pragma unroll
                for (int mt = 0; mt < 4; ++mt)
                    acc[mt][nt] = __builtin_amdgcn_mfma_f32_16x16x32_bf16(af[mt], bf[nt], acc[mt][nt], 0, 0, 0);
        }

        if (kt < 12) {
            union { short8 s; unsigned int u[4]; } af;
            af.u[0] = pack2_bf16(h0.x, h0.y);
            af.u[1] = pack2_bf16(h0.z, h0.w);
            af.u[2] = pack2_bf16(h1.x, h1.y);
            af.u[3] = pack2_bf16(h1.z, h1.w);
            *(short8*)((kt & 1) ? sdst0 : sdst1) = af.s;
            __syncthreads();
        }
    }

    // ---- epilogue: bias + relu + exp, row sums across 8 waves, scale, store ----
    float bias_v[4];
    #pragma unroll
    for (int nt = 0; nt < 4; ++nt)
        bias_v[nt] = bias[w * 64 + nt * 16 + lid];

    #pragma unroll
    for (int mt = 0; mt < 4; ++mt) {
        #pragma unroll
        for (int reg = 0; reg < 4; ++reg) {
            float s = 0.f;
            #pragma unroll
            for (int nt = 0; nt < 4; ++nt) {
                float v = acc[mt][nt][reg] + bias_v[nt];
                v = fmaxf(v, 0.f);
                float e = __expf(v);
                acc[mt][nt][reg] = e;
                s += e;
            }
            s += __shfl_xor(s, 1, 64);
            s += __shfl_xor(s, 2, 64);
            s += __shfl_xor(s, 4, 64);
            s += __shfl_xor(s, 8, 64);
            if (lid == 0) part[w][mt * 16 + quad * 4 + reg] = s;
        }
    }
    __syncthreads();

    #pragma unroll
    for (int mt = 0; mt < 4; ++mt) {
        #pragma unroll
        for (int reg = 0; reg < 4; ++reg) {
            const int row = mt * 16 + quad * 4 + reg;
            float tot = 0.f;
            #pragma unroll
            for (int ww = 0; ww < 8; ++ww) tot += part[ww][row];
            const float inv = 1.0f / tot;
            #pragma unroll
            for (int nt = 0; nt < 4; ++nt)
                out[(size_t)(m_base + row) * 512 + w * 64 + nt * 16 + lid] = acc[mt][nt][reg] * inv;
        }
    }
}

extern "C" void kernel_launch(void* const* d_in, const int* in_sizes, int n_in,
                              void* d_out, int out_size, void* d_ws, size_t ws_size,
                              hipStream_t stream) {
    const float* x    = (const float*)d_in[0];
    const float* c1   = (const float*)d_in[1];
    const float* c2   = (const float*)d_in[2];
    const float* c3   = (const float*)d_in[3];
    const float* c4   = (const float*)d_in[4];
    const float* bias = (const float*)d_in[5];
    float* out = (float*)d_out;
    short* wpb = (short*)d_ws;

    prep_all<<<225, 256, 0, stream>>>(c1, c2, c3, c4, wpb);
    tt_gemm <<<256, 512, 0, stream>>>(x, wpb, bias, out);
}